// Round 10
// baseline (212.341 us; speedup 1.0000x reference)
//
#include <hip/hip_runtime.h>
#include <hip/hip_bf16.h>
#include <cstdint>
#include <cstddef>

typedef __bf16 bf16x8 __attribute__((ext_vector_type(8)));
typedef float f32x4 __attribute__((ext_vector_type(4)));
typedef float f32x16 __attribute__((ext_vector_type(16)));
typedef unsigned short ushort8 __attribute__((ext_vector_type(8)));

#define MFMA16(a, b, c) __builtin_amdgcn_mfma_f32_16x16x32_bf16(a, b, c, 0, 0, 0)
#define MFMA32(a, b, c) __builtin_amdgcn_mfma_f32_32x32x16_bf16(a, b, c, 0, 0, 0)

__device__ __forceinline__ void gll16(const void* g, void* l) {
  __builtin_amdgcn_global_load_lds((__attribute__((address_space(1))) unsigned int*)g,
                                   (__attribute__((address_space(3))) unsigned int*)l,
                                   16, 0, 0);
}

__device__ __forceinline__ float exp2_raw(float x) {
  return __builtin_amdgcn_exp2f(x);
}

__device__ __forceinline__ bf16x8 pack8(float a0, float a1, float a2, float a3,
                                        float a4, float a5, float a6, float a7) {
  unsigned w0, w1, w2, w3;
  asm("v_cvt_pk_bf16_f32 %0, %1, %2" : "=v"(w0) : "v"(a0), "v"(a1));
  asm("v_cvt_pk_bf16_f32 %0, %1, %2" : "=v"(w1) : "v"(a2), "v"(a3));
  asm("v_cvt_pk_bf16_f32 %0, %1, %2" : "=v"(w2) : "v"(a4), "v"(a5));
  asm("v_cvt_pk_bf16_f32 %0, %1, %2" : "=v"(w3) : "v"(a6), "v"(a7));
  asm("v_permlane32_swap_b32 %0, %1" : "+v"(w0), "+v"(w2));
  asm("v_permlane32_swap_b32 %0, %1" : "+v"(w1), "+v"(w3));
  union { unsigned u[4]; bf16x8 v; } r;
  r.u[0] = w0; r.u[1] = w1; r.u[2] = w2; r.u[3] = w3;
  return r.v;
}

// ---------------- elementwise / prep kernels ----------------

__global__ void cvt_x(const float* __restrict__ in, __bf16* __restrict__ out) {
  int i = (blockIdx.x * 256 + threadIdx.x) * 8;
  float4 a = *(const float4*)(in + i);
  float4 c = *(const float4*)(in + i + 4);
  bf16x8 r;
  r[0] = (__bf16)a.x; r[1] = (__bf16)a.y; r[2] = (__bf16)a.z; r[3] = (__bf16)a.w;
  r[4] = (__bf16)c.x; r[5] = (__bf16)c.y; r[6] = (__bf16)c.z; r[7] = (__bf16)c.w;
  *(bf16x8*)(out + i) = r;
}

__global__ void rope_tab_k(float2* __restrict__ tab) {
  int i = blockIdx.x * 256 + threadIdx.x;   // 2048*32 = 65536
  int t = i >> 5, ii = i & 31;
  float invf = exp2f(-(float)ii * (13.287712379549449f / 32.0f));
  float a = (float)t * invf;
  tab[i] = make_float2(cosf(a), sinf(a));
}

__global__ void transp_bf16(const float* __restrict__ W, __bf16* __restrict__ Wt,
                            int K, int N) {
  __shared__ float tile[32][33];
  int n0 = blockIdx.x * 32, k0 = blockIdx.y * 32;
  int tx = threadIdx.x & 31, ty = threadIdx.x >> 5;
  #pragma unroll
  for (int r = ty; r < 32; r += 8)
    tile[r][tx] = W[(size_t)(k0 + r) * N + n0 + tx];
  __syncthreads();
  #pragma unroll
  for (int r = ty; r < 32; r += 8)
    Wt[(size_t)(n0 + r) * K + k0 + tx] = (__bf16)tile[tx][r];
}

__global__ void transp_v(const __bf16* __restrict__ in, __bf16* __restrict__ out) {
  __shared__ unsigned short tile[64][72];
  const int bh = blockIdx.y, t0 = blockIdx.x * 64;
  const int tid = threadIdx.x;
  const int r = tid >> 3, c = (tid & 7) * 8;
  const __bf16* src = in + ((size_t)bh * 2048 + t0) * 64;
  ushort8 a = *(const ushort8*)(src + (size_t)r * 64 + c);
  ushort8 b = *(const ushort8*)(src + (size_t)(r + 32) * 64 + c);
  #pragma unroll
  for (int e = 0; e < 8; ++e) { tile[c + e][r] = a[e]; tile[c + e][r + 32] = b[e]; }
  __syncthreads();
  const int d = tid >> 3, tc = tid & 7;
  __bf16* dst0 = out + ((size_t)bh * 64 + d) * 2048 + t0;
  *(ushort8*)(dst0 + tc * 8) = *(const ushort8*)&tile[d][tc * 8];
  __bf16* dst1 = out + ((size_t)bh * 64 + d + 32) * 2048 + t0;
  *(ushort8*)(dst1 + tc * 8) = *(const ushort8*)&tile[d + 32][tc * 8];
}

// ---- gemm8p: 256x256, BK=64, 8 waves, m201-style 8-phase region-recycled pipeline ----
// All 8 waves compute one 128x128 C-quadrant per phase (wave piece: 32 rows x 64 cols).
// LDS: bufX | bufY, each {A0,A1,B0,B1} 16KB halves = 64KB -> 128KB total.
// Ledger: stage 1 half/phase (2 gll16/thread); vmcnt(4) gates before p0/p4, vmcnt(0)
// only at the last iteration's GATE_B. Stages target regions retired by the previous
// phase's barrier (verified half-death map in comments below).

template <int QM, int QN>
__device__ __forceinline__ void compute_quad(
    const char* buf, f32x4 (&acc)[2][2][2][4],
    int wrp, int wcp, int l15, int g, int fr0, int fr1) {
  const char* Ar = buf + QM * 16384;
  const char* Br = buf + 32768 + QN * 16384;
  bf16x8 af[2][2], bfr[4][2];
  #pragma unroll
  for (int m = 0; m < 2; ++m) {
    int fx = (m & 1) ? fr1 : fr0;
    #pragma unroll
    for (int kk = 0; kk < 2; ++kk)
      af[m][kk] = *(const bf16x8*)(Ar + (wrp * 32 + m * 16 + l15) * 128 +
                                   (((kk * 4 + g) ^ fx) << 4));
  }
  #pragma unroll
  for (int n = 0; n < 4; ++n) {
    int fx = (n & 1) ? fr1 : fr0;
    #pragma unroll
    for (int kk = 0; kk < 2; ++kk)
      bfr[n][kk] = *(const bf16x8*)(Br + (wcp * 64 + n * 16 + l15) * 128 +
                                    (((kk * 4 + g) ^ fx) << 4));
  }
  __builtin_amdgcn_s_setprio(1);
  #pragma unroll
  for (int kk = 0; kk < 2; ++kk)
    #pragma unroll
    for (int m = 0; m < 2; ++m)
      #pragma unroll
      for (int n = 0; n < 4; ++n)
        acc[QM][QN][m][n] = MFMA16(af[m][kk], bfr[n][kk], acc[QM][QN][m][n]);
  __builtin_amdgcn_s_setprio(0);
}

template <int EPI>
__global__ __launch_bounds__(512, 1) void gemm8p(
    const __bf16* __restrict__ A, const __bf16* __restrict__ Bt,
    const float* __restrict__ bias, float* __restrict__ Cf,
    __bf16* __restrict__ qp, __bf16* __restrict__ kp, __bf16* __restrict__ vp,
    const float2* __restrict__ ctab, int M, int N, int K) {
  extern __shared__ __align__(16) char smem[];
  const int tid = threadIdx.x;
  const int w = tid >> 6, l = tid & 63, l15 = l & 15, g = l >> 4;
  const int wrp = w & 3;    // row piece (32 rows) within quadrant
  const int wcp = w >> 2;   // col piece (64 cols) within quadrant

  // XCD-aware block swizzle (nwg % 8 == 0 by construction)
  const int nbx = gridDim.x;
  const int nwg = nbx * gridDim.y;
  const int orig = blockIdx.y * nbx + blockIdx.x;
  const int wgid = (orig & 7) * (nwg >> 3) + (orig >> 3);
  const int brow = (wgid / nbx) * 256, bcol = (wgid % nbx) * 256;

  const int NT = K >> 6, NITER = NT >> 1;

  // staging: thread covers row j*64 + (tid>>3), chunk (tid&7) ^ f(row)
  const int srow = tid >> 3;
  const int sf = ((tid >> 3) & 7) ^ (((tid >> 6) & 3) << 1);
  const int schunk = ((tid & 7) ^ sf) << 4;
  const size_t K2 = (size_t)K * 2;

  // frag-read swizzle values
  const int fr0 = (l15 & 7) ^ (((l15 >> 3) & 3) << 1);
  const int fr1 = (l15 & 7) ^ ((((l15 >> 3) + 2) & 3) << 1);

  f32x4 acc[2][2][2][4] = {};   // [qm][qn][m][n]

#define STAGE_A8(tile, half, bufoff) do {                                              \
    const char* _s = (const char*)A +                                                  \
      ((size_t)(brow + (half) * 128 + srow) * K + (tile) * 64) * 2 + schunk;           \
    gll16(_s, smem + (bufoff) + (half) * 16384 + tid * 16);                            \
    gll16(_s + 64 * K2, smem + (bufoff) + (half) * 16384 + 8192 + tid * 16);           \
  } while (0)
#define STAGE_B8(tile, half, bufoff) do {                                              \
    const char* _s = (const char*)Bt +                                                 \
      ((size_t)(bcol + (half) * 128 + srow) * K + (tile) * 64) * 2 + schunk;           \
    gll16(_s, smem + (bufoff) + 32768 + (half) * 16384 + tid * 16);                    \
    gll16(_s + 64 * K2, smem + (bufoff) + 32768 + (half) * 16384 + 8192 + tid * 16);   \
  } while (0)
#define BARRIER() do { asm volatile("" ::: "memory");                                  \
    __builtin_amdgcn_s_barrier(); asm volatile("" ::: "memory"); } while (0)

  // prologue ledger (12 loads): t0.A0 t0.B0 t0.A1 t0.B1 t1.A0 t1.B0
  STAGE_A8(0, 0, 0); STAGE_B8(0, 0, 0); STAGE_A8(0, 1, 0); STAGE_B8(0, 1, 0);
  STAGE_A8(1, 0, 65536); STAGE_B8(1, 0, 65536);

  for (int it = 0; it < NITER; ++it) {
    const int t = it * 2;
    const bool more2 = (t + 2 < NT), more3 = (t + 3 < NT);
    // GATE_A: tile t fully landed (last 4 outstanding = t+1.A0/B0)
    asm volatile("s_waitcnt vmcnt(4)" ::: "memory");
    BARRIER();
    // p0: q(0,0) of t [reads X.A0,X.B0]; stage (t+1).A1 -> Y.A1 (readers retired @p7 prev it)
    STAGE_A8(t + 1, 1, 65536);
    compute_quad<0, 0>(smem, acc, wrp, wcp, l15, g, fr0, fr1);
    BARRIER();
    // p1: q(0,1) [X.A0,X.B1]; stage (t+1).B1 -> Y.B1
    STAGE_B8(t + 1, 1, 65536);
    compute_quad<0, 1>(smem, acc, wrp, wcp, l15, g, fr0, fr1);
    BARRIER();
    // p2: q(1,0) [X.A1,X.B0]; X.A0 died @p1 -> stage (t+2).A0
    if (more2) STAGE_A8(t + 2, 0, 0);
    compute_quad<1, 0>(smem, acc, wrp, wcp, l15, g, fr0, fr1);
    BARRIER();
    // p3: q(1,1) [X.A1,X.B1]; X.B0 died @p2 -> stage (t+2).B0
    if (more2) STAGE_B8(t + 2, 0, 0);
    compute_quad<1, 1>(smem, acc, wrp, wcp, l15, g, fr0, fr1);
    BARRIER();
    // GATE_B: tile t+1 fully landed (last 4 outstanding = t+2.A0/B0); tail drains to 0
    if (it == NITER - 1) { asm volatile("s_waitcnt vmcnt(0)" ::: "memory"); }
    else                 { asm volatile("s_waitcnt vmcnt(4)" ::: "memory"); }
    BARRIER();
    // p4: q(0,0) of t+1 [Y.A0,Y.B0]; X.A1 died @p3 -> stage (t+2).A1
    if (more2) STAGE_A8(t + 2, 1, 0);
    compute_quad<0, 0>(smem + 65536, acc, wrp, wcp, l15, g, fr0, fr1);
    BARRIER();
    // p5: q(0,1) [Y.A0,Y.B1]; X.B1 died @p3 -> stage (t+2).B1
    if (more2) STAGE_B8(t + 2, 1, 0);
    compute_quad<0, 1>(smem + 65536, acc, wrp, wcp, l15, g, fr0, fr1);
    BARRIER();
    // p6: q(1,0) [Y.A1,Y.B0]; Y.A0 died @p5 -> stage (t+3).A0
    if (more3) STAGE_A8(t + 3, 0, 65536);
    compute_quad<1, 0>(smem + 65536, acc, wrp, wcp, l15, g, fr0, fr1);
    BARRIER();
    // p7: q(1,1) [Y.A1,Y.B1]; Y.B0 died @p6 -> stage (t+3).B0
    if (more3) STAGE_B8(t + 3, 0, 65536);
    compute_quad<1, 1>(smem + 65536, acc, wrp, wcp, l15, g, fr0, fr1);
    BARRIER();
  }
#undef STAGE_A8
#undef STAGE_B8
#undef BARRIER

  // epilogue
  #pragma unroll
  for (int qn = 0; qn < 2; ++qn) {
    const int colb = bcol + qn * 128 + wcp * 64;     // 64-aligned: one head (EPI=0)
    float bs[4];
    #pragma unroll
    for (int n = 0; n < 4; ++n) bs[n] = bias[colb + n * 16 + l15];
    if (EPI == 1) {
      #pragma unroll
      for (int qm = 0; qm < 2; ++qm)
        #pragma unroll
        for (int m = 0; m < 2; ++m)
          #pragma unroll
          for (int j = 0; j < 4; ++j) {
            int row = brow + qm * 128 + wrp * 32 + m * 16 + g * 4 + j;
            float* crow = Cf + (size_t)row * N + colb;
            #pragma unroll
            for (int n = 0; n < 4; ++n)
              crow[n * 16 + l15] = acc[qm][qn][m][n][j] + bs[n];
          }
    } else {
      const int which = colb >> 10;            // 0=q 1=k 2=v
      const int h = (colb & 1023) >> 6;
      __bf16* dst = (which == 0) ? qp : (which == 1) ? kp : vp;
      const float SCLQ = 0.18033688011112042f; // 1/sqrt(64) * log2(e) folded into q
      #pragma unroll
      for (int qm = 0; qm < 2; ++qm)
        #pragma unroll
        for (int m = 0; m < 2; ++m)
          #pragma unroll
          for (int j = 0; j < 4; ++j) {
            int row = brow + qm * 128 + wrp * 32 + m * 16 + g * 4 + j;
            int bb = row >> 11, t = row & 2047;
            float v0 = acc[qm][qn][0][m * 0 + 0][j]; // placeholder, replaced below
            (void)v0;
            float a0 = acc[qm][qn][m][0][j] + bs[0];
            float a1 = acc[qm][qn][m][1][j] + bs[1];
            float a2 = acc[qm][qn][m][2][j] + bs[2];
            float a3 = acc[qm][qn][m][3][j] + bs[3];
            if (which < 2) {
              float2 cs0 = ctab[t * 32 + l15];
              float2 cs1 = ctab[t * 32 + 16 + l15];
              float r0 = a0 * cs0.x - a2 * cs0.y;
              float r2 = a2 * cs0.x + a0 * cs0.y;
              float r1 = a1 * cs1.x - a3 * cs1.y;
              float r3 = a3 * cs1.x + a1 * cs1.y;
              a0 = r0; a1 = r1; a2 = r2; a3 = r3;
            }
            if (which == 0) { a0 *= SCLQ; a1 *= SCLQ; a2 *= SCLQ; a3 *= SCLQ; }
            __bf16* orow = dst + ((size_t)(bb * 16 + h) * 2048 + t) * 64;
            orow[l15]      = (__bf16)a0;
            orow[16 + l15] = (__bf16)a1;
            orow[32 + l15] = (__bf16)a2;
            orow[48 + l15] = (__bf16)a3;
          }
    }
  }
}

// ---- GEMM 128x128 (R9 structure, kept for the proj GEMM) ----
template <int EPI>
__global__ __launch_bounds__(256, 4) void gemm_bt(
    const __bf16* __restrict__ A, const __bf16* __restrict__ Bt,
    const float* __restrict__ bias, float* __restrict__ Cf,
    __bf16* __restrict__ qp, __bf16* __restrict__ kp, __bf16* __restrict__ vp,
    const float2* __restrict__ ctab, int M, int N, int K) {
  __shared__ __align__(16) char smem[32768];
  const int tid = threadIdx.x;
  const int w = tid >> 6, l = tid & 63, l15 = l & 15, g = l >> 4;
  const int wr = w >> 1, wc = w & 1;
  const int brow = blockIdx.y * 128, bcol = blockIdx.x * 128;

  f32x4 acc[4][4] = {};
  const int rsub = tid >> 3;
  const int sf   = (rsub & 7) ^ (((rsub >> 3) & 3) << 1);
  const int schunk = (((tid & 7) ^ sf) << 4);
  const int fr0 = (l15 & 7) ^ (((l15 >> 3) & 3) << 1);
  const int fr1 = (l15 & 7) ^ ((((l15 >> 3) + 2) & 3) << 1);

  for (int kt = 0; kt < K; kt += 64) {
    __syncthreads();
    #pragma unroll
    for (int i = 0; i < 4; ++i) {
      const char* ga = (const char*)(A + (size_t)(brow + i * 32 + rsub) * K + kt) + schunk;
      gll16(ga, smem + i * 4096 + tid * 16);
      const char* gb = (const char*)(Bt + (size_t)(bcol + i * 32 + rsub) * K + kt) + schunk;
      gll16(gb, smem + 16384 + i * 4096 + tid * 16);
    }
    __syncthreads();
    #pragma unroll
    for (int kk = 0; kk < 2; ++kk) {
      bf16x8 af[4], bfr[4];
      #pragma unroll
      for (int m = 0; m < 4; ++m) {
        int fx = (m & 1) ? fr1 : fr0;
        af[m] = *(const bf16x8*)(smem + (wr * 64 + m * 16 + l15) * 128 +
                                 (((kk * 4 + g) ^ fx) << 4));
      }
      #pragma unroll
      for (int n = 0; n < 4; ++n) {
        int fx = (n & 1) ? fr1 : fr0;
        bfr[n] = *(const bf16x8*)(smem + 16384 + (wc * 64 + n * 16 + l15) * 128 +
                                  (((kk * 4 + g) ^ fx) << 4));
      }
      __builtin_amdgcn_s_setprio(1);
      #pragma unroll
      for (int m = 0; m < 4; ++m)
        #pragma unroll
        for (int n = 0; n < 4; ++n)
          acc[m][n] = MFMA16(af[m], bfr[n], acc[m][n]);
      __builtin_amdgcn_s_setprio(0);
    }
  }

  const int colb = bcol + wc * 64;
  float bs[4];
  #pragma unroll
  for (int n = 0; n < 4; ++n) bs[n] = bias[colb + n * 16 + l15];

  if (EPI == 1) {
    #pragma unroll
    for (int m = 0; m < 4; ++m)
      #pragma unroll
      for (int j = 0; j < 4; ++j) {
        int row = brow + wr * 64 + m * 16 + g * 4 + j;
        float* crow = Cf + (size_t)row * N + colb;
        #pragma unroll
        for (int n = 0; n < 4; ++n)
          crow[n * 16 + l15] = acc[m][n][j] + bs[n];
      }
  } else {
    const int which = colb >> 10;
    const int h = (colb & 1023) >> 6;
    __bf16* dst = (which == 0) ? qp : (which == 1) ? kp : vp;
    const float SCLQ = 0.18033688011112042f;
    #pragma unroll
    for (int m = 0; m < 4; ++m)
      #pragma unroll
      for (int j = 0; j < 4; ++j) {
        int row = brow + wr * 64 + m * 16 + g * 4 + j;
        int bb = row >> 11, t = row & 2047;
        float v0 = acc[m][0][j] + bs[0];
        float v1 = acc[m][1][j] + bs[1];
        float v2 = acc[m][2][j] + bs[2];
        float v3 = acc[m][3][j] + bs[3];
        if (which < 2) {
          float2 cs0 = ctab[t * 32 + l15];
          float2 cs1 = ctab[t * 32 + 16 + l15];
          float r0 = v0 * cs0.x - v2 * cs0.y;
          float r2 = v2 * cs0.x + v0 * cs0.y;
          float r1 = v1 * cs1.x - v3 * cs1.y;
          float r3 = v3 * cs1.x + v1 * cs1.y;
          v0 = r0; v1 = r1; v2 = r2; v3 = r3;
        }
        if (which == 0) { v0 *= SCLQ; v1 *= SCLQ; v2 *= SCLQ; v3 *= SCLQ; }
        __bf16* orow = dst + ((size_t)(bb * 16 + h) * 2048 + t) * 64;
        orow[l15]      = (__bf16)v0;
        orow[16 + l15] = (__bf16)v1;
        orow[32 + l15] = (__bf16)v2;
        orow[48 + l15] = (__bf16)v3;
      }
  }
}

// ---------------- flash attention: 32x32 swapped-QK^T, in-register softmax ------
__global__ __launch_bounds__(256, 4) void flash_attn(
    const __bf16* __restrict__ q, const __bf16* __restrict__ k,
    const __bf16* __restrict__ vt, __bf16* __restrict__ o) {
  __shared__ __align__(16) char smem[32768];  // K0 V0 | K1 V1 (8KB each)
  const int id = blockIdx.x;
  const int nid = (id & 7) * 128 + (id >> 3);   // XCD-chunked swizzle
  const int bh = nid >> 4, qb = nid & 15;
  const int b = bh >> 4, h = bh & 15;
  const int tid = threadIdx.x, w = tid >> 6, l = tid & 63;
  const int l31 = l & 31, hi = l >> 5;

  const char* kbase  = (const char*)(k  + (size_t)bh * 2048 * 64);
  const char* vtbase = (const char*)(vt + (size_t)bh * 64 * 2048);

  bf16x8 qf[4];
  const int qrow0 = qb * 128 + w * 32;
  #pragma unroll
  for (int ks = 0; ks < 4; ++ks)
    qf[ks] = *(const bf16x8*)(q + (size_t)bh * 2048 * 64 +
                              (size_t)(qrow0 + l31) * 64 + ks * 16 + hi * 8);

  f32x16 accO[2] = {};
  float lr = 0.f;

  const int koff[2] = { 0, 16384 };
  const int voff[2] = { 8192, 24576 };

  const int srow = tid >> 3;
  const int ssw  = (((tid & 7) ^ ((tid >> 3) & 7) ^ (((tid >> 6) & 3) << 1)) << 4);
  const int swz  = (((l & 7) ^ (((l >> 3) & 3) << 1)) << 4);

  gll16(kbase + srow * 128 + ssw,                  smem + koff[0] + tid * 16);
  gll16(kbase + (srow + 32) * 128 + ssw,           smem + koff[0] + 4096 + tid * 16);
  gll16(vtbase + (size_t)srow * 4096 + ssw,        smem + voff[0] + tid * 16);
  gll16(vtbase + (size_t)(srow + 32) * 4096 + ssw, smem + voff[0] + 4096 + tid * 16);
  __syncthreads();

  for (int t = 0; t < 32; ++t) {
    const int cur = t & 1;
    char* Kc = smem + koff[cur];
    char* Vc = smem + voff[cur];
    if (t < 31) {
      char* Kn = smem + koff[cur ^ 1];
      char* Vn = smem + voff[cur ^ 1];
      const char* gk = kbase + (size_t)(t + 1) * 8192;
      gll16(gk + srow * 128 + ssw,        Kn + tid * 16);
      gll16(gk + (srow + 32) * 128 + ssw, Kn + 4096 + tid * 16);
      const char* gv = vtbase + (size_t)(t + 1) * 128;
      gll16(gv + (size_t)srow * 4096 + ssw,        Vn + tid * 16);
      gll16(gv + (size_t)(srow + 32) * 4096 + ssw, Vn + 4096 + tid * 16);
    }

    f32x16 st0 = {}, st1 = {};
    __builtin_amdgcn_s_setprio(1);
    #pragma unroll
    for (int ks = 0; ks < 4; ++ks) {
      bf16x8 kf0 = *(const bf16x8*)(Kc + (l31) * 128 + ((ks * 32 + hi * 16) ^ swz));
      bf16x8 kf1 = *(const bf16x8*)(Kc + (32 + l31) * 128 + ((ks * 32 + hi * 16) ^ swz));
      st0 = MFMA32(kf0, qf[ks], st0);
      st1 = MFMA32(kf1, qf[ks], st1);
    }
    __builtin_amdgcn_s_setprio(0);

    bf16x8 pa[4];
    {
      float p[16];
      #pragma unroll
      for (int r = 0; r < 16; ++r) p[r] = exp2_raw(st0[r]);
      lr += (((p[0] + p[1]) + (p[2] + p[3])) + ((p[4] + p[5]) + (p[6] + p[7]))) +
            (((p[8] + p[9]) + (p[10] + p[11])) + ((p[12] + p[13]) + (p[14] + p[15])));
      pa[0] = pack8(p[0], p[1], p[2], p[3], p[4], p[5], p[6], p[7]);
      pa[1] = pack8(p[8], p[9], p[10], p[11], p[12], p[13], p[14], p[15]);
    }
    {
      float p[16];
      #pragma unroll
      for (int r = 0; r < 16; ++r) p[r] = exp2_raw(st1[r]);
      lr += (((p[0] + p[1]) + (p[2] + p[3])) + ((p[4] + p[5]) + (p[6] + p[7]))) +
            (((p[8] + p[9]) + (p[10] + p[11])) + ((p[12] + p[13]) + (p[14] + p[15])));
      pa[2] = pack8(p[0], p[1], p[2], p[3], p[4], p[5], p[6], p[7]);
      pa[3] = pack8(p[8], p[9], p[10], p[11], p[12], p[13], p[14], p[15]);
    }

    __builtin_amdgcn_s_setprio(1);
    #pragma unroll
    for (int ks = 0; ks < 4; ++ks) {
      bf16x8 vf0 = *(const bf16x8*)(Vc + (l31) * 128 + ((ks * 32 + hi * 16) ^ swz));
      bf16x8 vf1 = *(const bf16x8*)(Vc + (32 + l31) * 128 + ((ks * 32 + hi * 16) ^ swz));
      accO[0] = MFMA32(pa[ks], vf0, accO[0]);
      accO[1] = MFMA32(pa[ks], vf1, accO[1]);
    }
    __builtin_amdgcn_s_setprio(0);
    __syncthreads();
  }

  float lrf = lr + __shfl_xor(lr, 32);
  __bf16* obase = o + (size_t)(b * 2048) * 1024 + h * 64;
  #pragma unroll
  for (int r = 0; r < 16; ++r) {
    int qloc = (r & 3) + 8 * (r >> 2) + 4 * hi;
    float inv = 1.0f / __shfl(lrf, qloc);
    __bf16* orow = obase + (size_t)(qrow0 + qloc) * 1024;
    orow[l31]      = (__bf16)(accO[0][r] * inv);
    orow[32 + l31] = (__bf16)(accO[1][r] * inv);
  }
}

// ---------------- launch ----------------

extern "C" void kernel_launch(void* const* d_in, const int* in_sizes, int n_in,
                              void* d_out, int out_size, void* d_ws, size_t ws_size,
                              hipStream_t stream) {
  const float* x     = (const float*)d_in[0];
  const float* Wqkv  = (const float*)d_in[1];
  const float* bqkv  = (const float*)d_in[2];
  const float* Wproj = (const float*)d_in[3];
  const float* bproj = (const float*)d_in[4];
  float* out = (float*)d_out;

  char* ws = (char*)d_ws;
  __bf16* xb  = (__bf16*)(ws);                   // 16 MB  x bf16 [8192][1024]; reused as vt
  __bf16* wtq = (__bf16*)(ws + 16777216);        // 6 MB   Wqkv^T [3072][1024]
  __bf16* wtp = (__bf16*)(ws + 23068672);        // 2 MB   Wproj^T [1024][1024]
  __bf16* qp  = (__bf16*)(ws + 25165824);        // 16 MB  q (B,H,T,64)
  __bf16* kp  = (__bf16*)(ws + 41943040);        // 16 MB  k
  __bf16* vp  = (__bf16*)(ws + 58720256);        // 16 MB  v
  __bf16* ao  = (__bf16*)(ws + 75497472);        // 16 MB  attn out [8192][1024]
  float2* ct  = (float2*)(ws + 92274688);        // 512 KB rope table
  __bf16* vtp = xb;                              // vt (B,H,64,T) — overwrites dead xb
  if (ws_size < 92798976) return;

  const int LDS8P = 131072;  // 2 buffers x 64KB
  hipFuncSetAttribute((const void*)gemm8p<0>,
                      hipFuncAttributeMaxDynamicSharedMemorySize, LDS8P);

  cvt_x<<<4096, 256, 0, stream>>>(x, xb);
  rope_tab_k<<<256, 256, 0, stream>>>(ct);
  transp_bf16<<<dim3(96, 32), 256, 0, stream>>>(Wqkv, wtq, 1024, 3072);
  transp_bf16<<<dim3(32, 32), 256, 0, stream>>>(Wproj, wtp, 1024, 1024);
  gemm8p<0><<<dim3(12, 32), 512, LDS8P, stream>>>(xb, wtq, bqkv, nullptr,
                                                  qp, kp, vp, ct, 8192, 3072, 1024);
  transp_v<<<dim3(32, 64), 256, 0, stream>>>(vp, vtp);
  flash_attn<<<1024, 256, 0, stream>>>(qp, kp, vtp, ao);
  gemm_bt<1><<<dim3(8, 64), 256, 0, stream>>>(ao, wtp, bproj, out, nullptr, nullptr,
                                              nullptr, nullptr, 8192, 1024, 1024);
}

// Round 11
// 212.271 us; speedup vs baseline: 1.0003x; 1.0003x over previous
//
#include <hip/hip_runtime.h>
#include <hip/hip_bf16.h>
#include <cstdint>
#include <cstddef>

typedef __bf16 bf16x8 __attribute__((ext_vector_type(8)));
typedef float f32x4 __attribute__((ext_vector_type(4)));
typedef float f32x16 __attribute__((ext_vector_type(16)));
typedef unsigned short ushort8 __attribute__((ext_vector_type(8)));

#define MFMA16(a, b, c) __builtin_amdgcn_mfma_f32_16x16x32_bf16(a, b, c, 0, 0, 0)
#define MFMA32(a, b, c) __builtin_amdgcn_mfma_f32_32x32x16_bf16(a, b, c, 0, 0, 0)

__device__ __forceinline__ void gll16(const void* g, void* l) {
  __builtin_amdgcn_global_load_lds((__attribute__((address_space(1))) unsigned int*)g,
                                   (__attribute__((address_space(3))) unsigned int*)l,
                                   16, 0, 0);
}

__device__ __forceinline__ float exp2_raw(float x) {
  return __builtin_amdgcn_exp2f(x);
}

__device__ __forceinline__ bf16x8 pack8(float a0, float a1, float a2, float a3,
                                        float a4, float a5, float a6, float a7) {
  unsigned w0, w1, w2, w3;
  asm("v_cvt_pk_bf16_f32 %0, %1, %2" : "=v"(w0) : "v"(a0), "v"(a1));
  asm("v_cvt_pk_bf16_f32 %0, %1, %2" : "=v"(w1) : "v"(a2), "v"(a3));
  asm("v_cvt_pk_bf16_f32 %0, %1, %2" : "=v"(w2) : "v"(a4), "v"(a5));
  asm("v_cvt_pk_bf16_f32 %0, %1, %2" : "=v"(w3) : "v"(a6), "v"(a7));
  asm("v_permlane32_swap_b32 %0, %1" : "+v"(w0), "+v"(w2));
  asm("v_permlane32_swap_b32 %0, %1" : "+v"(w1), "+v"(w3));
  union { unsigned u[4]; bf16x8 v; } r;
  r.u[0] = w0; r.u[1] = w1; r.u[2] = w2; r.u[3] = w3;
  return r.v;
}

// ---------------- elementwise / prep kernels ----------------

__global__ void cvt_x(const float* __restrict__ in, __bf16* __restrict__ out) {
  int i = (blockIdx.x * 256 + threadIdx.x) * 8;
  float4 a = *(const float4*)(in + i);
  float4 c = *(const float4*)(in + i + 4);
  bf16x8 r;
  r[0] = (__bf16)a.x; r[1] = (__bf16)a.y; r[2] = (__bf16)a.z; r[3] = (__bf16)a.w;
  r[4] = (__bf16)c.x; r[5] = (__bf16)c.y; r[6] = (__bf16)c.z; r[7] = (__bf16)c.w;
  *(bf16x8*)(out + i) = r;
}

__global__ void rope_tab_k(float2* __restrict__ tab) {
  int i = blockIdx.x * 256 + threadIdx.x;   // 2048*32 = 65536
  int t = i >> 5, ii = i & 31;
  float invf = exp2f(-(float)ii * (13.287712379549449f / 32.0f));
  float a = (float)t * invf;
  tab[i] = make_float2(cosf(a), sinf(a));
}

__global__ void transp_bf16(const float* __restrict__ W, __bf16* __restrict__ Wt,
                            int K, int N) {
  __shared__ float tile[32][33];
  int n0 = blockIdx.x * 32, k0 = blockIdx.y * 32;
  int tx = threadIdx.x & 31, ty = threadIdx.x >> 5;
  #pragma unroll
  for (int r = ty; r < 32; r += 8)
    tile[r][tx] = W[(size_t)(k0 + r) * N + n0 + tx];
  __syncthreads();
  #pragma unroll
  for (int r = ty; r < 32; r += 8)
    Wt[(size_t)(n0 + r) * K + k0 + tx] = (__bf16)tile[tx][r];
}

__global__ void transp_v(const __bf16* __restrict__ in, __bf16* __restrict__ out) {
  __shared__ unsigned short tile[64][72];
  const int bh = blockIdx.y, t0 = blockIdx.x * 64;
  const int tid = threadIdx.x;
  const int r = tid >> 3, c = (tid & 7) * 8;
  const __bf16* src = in + ((size_t)bh * 2048 + t0) * 64;
  ushort8 a = *(const ushort8*)(src + (size_t)r * 64 + c);
  ushort8 b = *(const ushort8*)(src + (size_t)(r + 32) * 64 + c);
  #pragma unroll
  for (int e = 0; e < 8; ++e) { tile[c + e][r] = a[e]; tile[c + e][r + 32] = b[e]; }
  __syncthreads();
  const int d = tid >> 3, tc = tid & 7;
  __bf16* dst0 = out + ((size_t)bh * 64 + d) * 2048 + t0;
  *(ushort8*)(dst0 + tc * 8) = *(const ushort8*)&tile[d][tc * 8];
  __bf16* dst1 = out + ((size_t)bh * 64 + d + 32) * 2048 + t0;
  *(ushort8*)(dst1 + tc * 8) = *(const ushort8*)&tile[d + 32][tc * 8];
}

// ---- gemm8p: 256x256, BK=64, 8 waves, m201-style 8-phase region-recycled pipeline ----
// All 8 waves compute one 128x128 C-quadrant per phase (wave piece: 32 rows x 64 cols).
// LDS: bufX | bufY, each {A0,A1,B0,B1} 16KB halves = 64KB -> 128KB total.
// Ledger: stage 1 half/phase (2 gll16/thread); vmcnt(4) gates before p0/p4, vmcnt(0)
// only at the last iteration's GATE_B. Stages target regions retired by the previous
// phase's barrier (verified half-death map in comments below).

template <int QM, int QN>
__device__ __forceinline__ void compute_quad(
    const char* buf, f32x4 (&acc)[2][2][2][4],
    int wrp, int wcp, int l15, int g, int fr0, int fr1) {
  const char* Ar = buf + QM * 16384;
  const char* Br = buf + 32768 + QN * 16384;
  bf16x8 af[2][2], bfr[4][2];
  #pragma unroll
  for (int m = 0; m < 2; ++m) {
    int fx = (m & 1) ? fr1 : fr0;
    #pragma unroll
    for (int kk = 0; kk < 2; ++kk)
      af[m][kk] = *(const bf16x8*)(Ar + (wrp * 32 + m * 16 + l15) * 128 +
                                   (((kk * 4 + g) ^ fx) << 4));
  }
  #pragma unroll
  for (int n = 0; n < 4; ++n) {
    int fx = (n & 1) ? fr1 : fr0;
    #pragma unroll
    for (int kk = 0; kk < 2; ++kk)
      bfr[n][kk] = *(const bf16x8*)(Br + (wcp * 64 + n * 16 + l15) * 128 +
                                    (((kk * 4 + g) ^ fx) << 4));
  }
  __builtin_amdgcn_s_setprio(1);
  #pragma unroll
  for (int kk = 0; kk < 2; ++kk)
    #pragma unroll
    for (int m = 0; m < 2; ++m)
      #pragma unroll
      for (int n = 0; n < 4; ++n)
        acc[QM][QN][m][n] = MFMA16(af[m][kk], bfr[n][kk], acc[QM][QN][m][n]);
  __builtin_amdgcn_s_setprio(0);
}

template <int EPI>
__global__ __launch_bounds__(512, 1) void gemm8p(
    const __bf16* __restrict__ A, const __bf16* __restrict__ Bt,
    const float* __restrict__ bias, float* __restrict__ Cf,
    __bf16* __restrict__ qp, __bf16* __restrict__ kp, __bf16* __restrict__ vp,
    const float2* __restrict__ ctab, int M, int N, int K) {
  extern __shared__ __align__(16) char smem[];
  const int tid = threadIdx.x;
  const int w = tid >> 6, l = tid & 63, l15 = l & 15, g = l >> 4;
  const int wrp = w & 3;    // row piece (32 rows) within quadrant
  const int wcp = w >> 2;   // col piece (64 cols) within quadrant

  // XCD-aware block swizzle (nwg % 8 == 0 by construction)
  const int nbx = gridDim.x;
  const int nwg = nbx * gridDim.y;
  const int orig = blockIdx.y * nbx + blockIdx.x;
  const int wgid = (orig & 7) * (nwg >> 3) + (orig >> 3);
  const int brow = (wgid / nbx) * 256, bcol = (wgid % nbx) * 256;

  const int NT = K >> 6, NITER = NT >> 1;

  // staging: thread covers row j*64 + (tid>>3), chunk (tid&7) ^ f(row)
  const int srow = tid >> 3;
  const int sf = ((tid >> 3) & 7) ^ (((tid >> 6) & 3) << 1);
  const int schunk = ((tid & 7) ^ sf) << 4;
  const size_t K2 = (size_t)K * 2;

  // frag-read swizzle values
  const int fr0 = (l15 & 7) ^ (((l15 >> 3) & 3) << 1);
  const int fr1 = (l15 & 7) ^ ((((l15 >> 3) + 2) & 3) << 1);

  f32x4 acc[2][2][2][4] = {};   // [qm][qn][m][n]

#define STAGE_A8(tile, half, bufoff) do {                                              \
    const char* _s = (const char*)A +                                                  \
      ((size_t)(brow + (half) * 128 + srow) * K + (tile) * 64) * 2 + schunk;           \
    gll16(_s, smem + (bufoff) + (half) * 16384 + tid * 16);                            \
    gll16(_s + 64 * K2, smem + (bufoff) + (half) * 16384 + 8192 + tid * 16);           \
  } while (0)
#define STAGE_B8(tile, half, bufoff) do {                                              \
    const char* _s = (const char*)Bt +                                                 \
      ((size_t)(bcol + (half) * 128 + srow) * K + (tile) * 64) * 2 + schunk;           \
    gll16(_s, smem + (bufoff) + 32768 + (half) * 16384 + tid * 16);                    \
    gll16(_s + 64 * K2, smem + (bufoff) + 32768 + (half) * 16384 + 8192 + tid * 16);   \
  } while (0)
#define BARRIER() do { asm volatile("" ::: "memory");                                  \
    __builtin_amdgcn_s_barrier(); asm volatile("" ::: "memory"); } while (0)

  // prologue ledger (12 loads): t0.A0 t0.B0 t0.A1 t0.B1 t1.A0 t1.B0
  STAGE_A8(0, 0, 0); STAGE_B8(0, 0, 0); STAGE_A8(0, 1, 0); STAGE_B8(0, 1, 0);
  STAGE_A8(1, 0, 65536); STAGE_B8(1, 0, 65536);

  for (int it = 0; it < NITER; ++it) {
    const int t = it * 2;
    const bool more2 = (t + 2 < NT), more3 = (t + 3 < NT);
    // GATE_A: tile t fully landed (last 4 outstanding = t+1.A0/B0)
    asm volatile("s_waitcnt vmcnt(4)" ::: "memory");
    BARRIER();
    // p0: q(0,0) of t [reads X.A0,X.B0]; stage (t+1).A1 -> Y.A1 (readers retired @p7 prev it)
    STAGE_A8(t + 1, 1, 65536);
    compute_quad<0, 0>(smem, acc, wrp, wcp, l15, g, fr0, fr1);
    BARRIER();
    // p1: q(0,1) [X.A0,X.B1]; stage (t+1).B1 -> Y.B1
    STAGE_B8(t + 1, 1, 65536);
    compute_quad<0, 1>(smem, acc, wrp, wcp, l15, g, fr0, fr1);
    BARRIER();
    // p2: q(1,0) [X.A1,X.B0]; X.A0 died @p1 -> stage (t+2).A0
    if (more2) STAGE_A8(t + 2, 0, 0);
    compute_quad<1, 0>(smem, acc, wrp, wcp, l15, g, fr0, fr1);
    BARRIER();
    // p3: q(1,1) [X.A1,X.B1]; X.B0 died @p2 -> stage (t+2).B0
    if (more2) STAGE_B8(t + 2, 0, 0);
    compute_quad<1, 1>(smem, acc, wrp, wcp, l15, g, fr0, fr1);
    BARRIER();
    // GATE_B: tile t+1 fully landed (last 4 outstanding = t+2.A0/B0); tail drains to 0
    if (it == NITER - 1) { asm volatile("s_waitcnt vmcnt(0)" ::: "memory"); }
    else                 { asm volatile("s_waitcnt vmcnt(4)" ::: "memory"); }
    BARRIER();
    // p4: q(0,0) of t+1 [Y.A0,Y.B0]; X.A1 died @p3 -> stage (t+2).A1
    if (more2) STAGE_A8(t + 2, 1, 0);
    compute_quad<0, 0>(smem + 65536, acc, wrp, wcp, l15, g, fr0, fr1);
    BARRIER();
    // p5: q(0,1) [Y.A0,Y.B1]; X.B1 died @p3 -> stage (t+2).B1
    if (more2) STAGE_B8(t + 2, 1, 0);
    compute_quad<0, 1>(smem + 65536, acc, wrp, wcp, l15, g, fr0, fr1);
    BARRIER();
    // p6: q(1,0) [Y.A1,Y.B0]; Y.A0 died @p5 -> stage (t+3).A0
    if (more3) STAGE_A8(t + 3, 0, 65536);
    compute_quad<1, 0>(smem + 65536, acc, wrp, wcp, l15, g, fr0, fr1);
    BARRIER();
    // p7: q(1,1) [Y.A1,Y.B1]; Y.B0 died @p6 -> stage (t+3).B0
    if (more3) STAGE_B8(t + 3, 0, 65536);
    compute_quad<1, 1>(smem + 65536, acc, wrp, wcp, l15, g, fr0, fr1);
    BARRIER();
  }
#undef STAGE_A8
#undef STAGE_B8
#undef BARRIER

  // epilogue
  #pragma unroll
  for (int qn = 0; qn < 2; ++qn) {
    const int colb = bcol + qn * 128 + wcp * 64;     // 64-aligned: one head (EPI=0)
    float bs[4];
    #pragma unroll
    for (int n = 0; n < 4; ++n) bs[n] = bias[colb + n * 16 + l15];
    if (EPI == 1) {
      #pragma unroll
      for (int qm = 0; qm < 2; ++qm)
        #pragma unroll
        for (int m = 0; m < 2; ++m)
          #pragma unroll
          for (int j = 0; j < 4; ++j) {
            int row = brow + qm * 128 + wrp * 32 + m * 16 + g * 4 + j;
            float* crow = Cf + (size_t)row * N + colb;
            #pragma unroll
            for (int n = 0; n < 4; ++n)
              crow[n * 16 + l15] = acc[qm][qn][m][n][j] + bs[n];
          }
    } else {
      const int which = colb >> 10;            // 0=q 1=k 2=v
      const int h = (colb & 1023) >> 6;
      __bf16* dst = (which == 0) ? qp : (which == 1) ? kp : vp;
      const float SCLQ = 0.18033688011112042f; // 1/sqrt(64) * log2(e) folded into q
      #pragma unroll
      for (int qm = 0; qm < 2; ++qm)
        #pragma unroll
        for (int m = 0; m < 2; ++m)
          #pragma unroll
          for (int j = 0; j < 4; ++j) {
            int row = brow + qm * 128 + wrp * 32 + m * 16 + g * 4 + j;
            int bb = row >> 11, t = row & 2047;
            float v0 = acc[qm][qn][0][m * 0 + 0][j]; // placeholder, replaced below
            (void)v0;
            float a0 = acc[qm][qn][m][0][j] + bs[0];
            float a1 = acc[qm][qn][m][1][j] + bs[1];
            float a2 = acc[qm][qn][m][2][j] + bs[2];
            float a3 = acc[qm][qn][m][3][j] + bs[3];
            if (which < 2) {
              float2 cs0 = ctab[t * 32 + l15];
              float2 cs1 = ctab[t * 32 + 16 + l15];
              float r0 = a0 * cs0.x - a2 * cs0.y;
              float r2 = a2 * cs0.x + a0 * cs0.y;
              float r1 = a1 * cs1.x - a3 * cs1.y;
              float r3 = a3 * cs1.x + a1 * cs1.y;
              a0 = r0; a1 = r1; a2 = r2; a3 = r3;
            }
            if (which == 0) { a0 *= SCLQ; a1 *= SCLQ; a2 *= SCLQ; a3 *= SCLQ; }
            __bf16* orow = dst + ((size_t)(bb * 16 + h) * 2048 + t) * 64;
            orow[l15]      = (__bf16)a0;
            orow[16 + l15] = (__bf16)a1;
            orow[32 + l15] = (__bf16)a2;
            orow[48 + l15] = (__bf16)a3;
          }
    }
  }
}

// ---- GEMM 128x128 (R9 structure, kept for the proj GEMM) ----
template <int EPI>
__global__ __launch_bounds__(256, 4) void gemm_bt(
    const __bf16* __restrict__ A, const __bf16* __restrict__ Bt,
    const float* __restrict__ bias, float* __restrict__ Cf,
    __bf16* __restrict__ qp, __bf16* __restrict__ kp, __bf16* __restrict__ vp,
    const float2* __restrict__ ctab, int M, int N, int K) {
  __shared__ __align__(16) char smem[32768];
  const int tid = threadIdx.x;
  const int w = tid >> 6, l = tid & 63, l15 = l & 15, g = l >> 4;
  const int wr = w >> 1, wc = w & 1;
  const int brow = blockIdx.y * 128, bcol = blockIdx.x * 128;

  f32x4 acc[4][4] = {};
  const int rsub = tid >> 3;
  const int sf   = (rsub & 7) ^ (((rsub >> 3) & 3) << 1);
  const int schunk = (((tid & 7) ^ sf) << 4);
  const int fr0 = (l15 & 7) ^ (((l15 >> 3) & 3) << 1);
  const int fr1 = (l15 & 7) ^ ((((l15 >> 3) + 2) & 3) << 1);

  for (int kt = 0; kt < K; kt += 64) {
    __syncthreads();
    #pragma unroll
    for (int i = 0; i < 4; ++i) {
      const char* ga = (const char*)(A + (size_t)(brow + i * 32 + rsub) * K + kt) + schunk;
      gll16(ga, smem + i * 4096 + tid * 16);
      const char* gb = (const char*)(Bt + (size_t)(bcol + i * 32 + rsub) * K + kt) + schunk;
      gll16(gb, smem + 16384 + i * 4096 + tid * 16);
    }
    __syncthreads();
    #pragma unroll
    for (int kk = 0; kk < 2; ++kk) {
      bf16x8 af[4], bfr[4];
      #pragma unroll
      for (int m = 0; m < 4; ++m) {
        int fx = (m & 1) ? fr1 : fr0;
        af[m] = *(const bf16x8*)(smem + (wr * 64 + m * 16 + l15) * 128 +
                                 (((kk * 4 + g) ^ fx) << 4));
      }
      #pragma unroll
      for (int n = 0; n < 4; ++n) {
        int fx = (n & 1) ? fr1 : fr0;
        bfr[n] = *(const bf16x8*)(smem + 16384 + (wc * 64 + n * 16 + l15) * 128 +
                                  (((kk * 4 + g) ^ fx) << 4));
      }
      __builtin_amdgcn_s_setprio(1);
      #pragma unroll
      for (int m = 0; m < 4; ++m)
        #pragma unroll
        for (int n = 0; n < 4; ++n)
          acc[m][n] = MFMA16(af[m], bfr[n], acc[m][n]);
      __builtin_amdgcn_s_setprio(0);
    }
  }

  const int colb = bcol + wc * 64;
  float bs[4];
  #pragma unroll
  for (int n = 0; n < 4; ++n) bs[n] = bias[colb + n * 16 + l15];

  if (EPI == 1) {
    #pragma unroll
    for (int m = 0; m < 4; ++m)
      #pragma unroll
      for (int j = 0; j < 4; ++j) {
        int row = brow + wr * 64 + m * 16 + g * 4 + j;
        float* crow = Cf + (size_t)row * N + colb;
        #pragma unroll
        for (int n = 0; n < 4; ++n)
          crow[n * 16 + l15] = acc[m][n][j] + bs[n];
      }
  } else {
    const int which = colb >> 10;
    const int h = (colb & 1023) >> 6;
    __bf16* dst = (which == 0) ? qp : (which == 1) ? kp : vp;
    const float SCLQ = 0.18033688011112042f;
    #pragma unroll
    for (int m = 0; m < 4; ++m)
      #pragma unroll
      for (int j = 0; j < 4; ++j) {
        int row = brow + wr * 64 + m * 16 + g * 4 + j;
        int bb = row >> 11, t = row & 2047;
        float v0 = acc[m][0][j] + bs[0];
        float v1 = acc[m][1][j] + bs[1];
        float v2 = acc[m][2][j] + bs[2];
        float v3 = acc[m][3][j] + bs[3];
        if (which < 2) {
          float2 cs0 = ctab[t * 32 + l15];
          float2 cs1 = ctab[t * 32 + 16 + l15];
          float r0 = v0 * cs0.x - v2 * cs0.y;
          float r2 = v2 * cs0.x + v0 * cs0.y;
          float r1 = v1 * cs1.x - v3 * cs1.y;
          float r3 = v3 * cs1.x + v1 * cs1.y;
          v0 = r0; v1 = r1; v2 = r2; v3 = r3;
        }
        if (which == 0) { v0 *= SCLQ; v1 *= SCLQ; v2 *= SCLQ; v3 *= SCLQ; }
        __bf16* orow = dst + ((size_t)(bb * 16 + h) * 2048 + t) * 64;
        orow[l15]      = (__bf16)v0;
        orow[16 + l15] = (__bf16)v1;
        orow[32 + l15] = (__bf16)v2;
        orow[48 + l15] = (__bf16)v3;
      }
  }
}

// ---------------- flash attention: 32x32 swapped-QK^T, in-register softmax ------
__global__ __launch_bounds__(256, 4) void flash_attn(
    const __bf16* __restrict__ q, const __bf16* __restrict__ k,
    const __bf16* __restrict__ vt, __bf16* __restrict__ o) {
  __shared__ __align__(16) char smem[32768];  // K0 V0 | K1 V1 (8KB each)
  const int id = blockIdx.x;
  const int nid = (id & 7) * 128 + (id >> 3);   // XCD-chunked swizzle
  const int bh = nid >> 4, qb = nid & 15;
  const int b = bh >> 4, h = bh & 15;
  const int tid = threadIdx.x, w = tid >> 6, l = tid & 63;
  const int l31 = l & 31, hi = l >> 5;

  const char* kbase  = (const char*)(k  + (size_t)bh * 2048 * 64);
  const char* vtbase = (const char*)(vt + (size_t)bh * 64 * 2048);

  bf16x8 qf[4];
  const int qrow0 = qb * 128 + w * 32;
  #pragma unroll
  for (int ks = 0; ks < 4; ++ks)
    qf[ks] = *(const bf16x8*)(q + (size_t)bh * 2048 * 64 +
                              (size_t)(qrow0 + l31) * 64 + ks * 16 + hi * 8);

  f32x16 accO[2] = {};
  float lr = 0.f;

  const int koff[2] = { 0, 16384 };
  const int voff[2] = { 8192, 24576 };

  const int srow = tid >> 3;
  const int ssw  = (((tid & 7) ^ ((tid >> 3) & 7) ^ (((tid >> 6) & 3) << 1)) << 4);
  const int swz  = (((l & 7) ^ (((l >> 3) & 3) << 1)) << 4);

  gll16(kbase + srow * 128 + ssw,                  smem + koff[0] + tid * 16);
  gll16(kbase + (srow + 32) * 128 + ssw,           smem + koff[0] + 4096 + tid * 16);
  gll16(vtbase + (size_t)srow * 4096 + ssw,        smem + voff[0] + tid * 16);
  gll16(vtbase + (size_t)(srow + 32) * 4096 + ssw, smem + voff[0] + 4096 + tid * 16);
  __syncthreads();

  for (int t = 0; t < 32; ++t) {
    const int cur = t & 1;
    char* Kc = smem + koff[cur];
    char* Vc = smem + voff[cur];
    if (t < 31) {
      char* Kn = smem + koff[cur ^ 1];
      char* Vn = smem + voff[cur ^ 1];
      const char* gk = kbase + (size_t)(t + 1) * 8192;
      gll16(gk + srow * 128 + ssw,        Kn + tid * 16);
      gll16(gk + (srow + 32) * 128 + ssw, Kn + 4096 + tid * 16);
      const char* gv = vtbase + (size_t)(t + 1) * 128;
      gll16(gv + (size_t)srow * 4096 + ssw,        Vn + tid * 16);
      gll16(gv + (size_t)(srow + 32) * 4096 + ssw, Vn + 4096 + tid * 16);
    }

    f32x16 st0 = {}, st1 = {};
    __builtin_amdgcn_s_setprio(1);
    #pragma unroll
    for (int ks = 0; ks < 4; ++ks) {
      bf16x8 kf0 = *(const bf16x8*)(Kc + (l31) * 128 + ((ks * 32 + hi * 16) ^ swz));
      bf16x8 kf1 = *(const bf16x8*)(Kc + (32 + l31) * 128 + ((ks * 32 + hi * 16) ^ swz));
      st0 = MFMA32(kf0, qf[ks], st0);
      st1 = MFMA32(kf1, qf[ks], st1);
    }
    __builtin_amdgcn_s_setprio(0);

    bf16x8 pa[4];
    {
      float p[16];
      #pragma unroll
      for (int r = 0; r < 16; ++r) p[r] = exp2_raw(st0[r]);
      lr += (((p[0] + p[1]) + (p[2] + p[3])) + ((p[4] + p[5]) + (p[6] + p[7]))) +
            (((p[8] + p[9]) + (p[10] + p[11])) + ((p[12] + p[13]) + (p[14] + p[15])));
      pa[0] = pack8(p[0], p[1], p[2], p[3], p[4], p[5], p[6], p[7]);
      pa[1] = pack8(p[8], p[9], p[10], p[11], p[12], p[13], p[14], p[15]);
    }
    {
      float p[16];
      #pragma unroll
      for (int r = 0; r < 16; ++r) p[r] = exp2_raw(st1[r]);
      lr += (((p[0] + p[1]) + (p[2] + p[3])) + ((p[4] + p[5]) + (p[6] + p[7]))) +
            (((p[8] + p[9]) + (p[10] + p[11])) + ((p[12] + p[13]) + (p[14] + p[15])));
      pa[2] = pack8(p[0], p[1], p[2], p[3], p[4], p[5], p[6], p[7]);
      pa[3] = pack8(p[8], p[9], p[10], p[11], p[12], p[13], p[14], p[15]);
    }

    __builtin_amdgcn_s_setprio(1);
    #pragma unroll
    for (int ks = 0; ks < 4; ++ks) {
      bf16x8 vf0 = *(const bf16x8*)(Vc + (l31) * 128 + ((ks * 32 + hi * 16) ^ swz));
      bf16x8 vf1 = *(const bf16x8*)(Vc + (32 + l31) * 128 + ((ks * 32 + hi * 16) ^ swz));
      accO[0] = MFMA32(pa[ks], vf0, accO[0]);
      accO[1] = MFMA32(pa[ks], vf1, accO[1]);
    }
    __builtin_amdgcn_s_setprio(0);
    __syncthreads();
  }

  float lrf = lr + __shfl_xor(lr, 32);
  __bf16* obase = o + (size_t)(b * 2048) * 1024 + h * 64;
  #pragma unroll
  for (int r = 0; r < 16; ++r) {
    int qloc = (r & 3) + 8 * (r >> 2) + 4 * hi;
    float inv = 1.0f / __shfl(lrf, qloc);
    __bf16* orow = obase + (size_t)(qrow0 + qloc) * 1024;
    orow[l31]      = (__bf16)(accO[0][r] * inv);
    orow[32 + l31] = (__bf16)(accO[1][r] * inv);
  }
}

// ---------------- launch ----------------

extern "C" void kernel_launch(void* const* d_in, const int* in_sizes, int n_in,
                              void* d_out, int out_size, void* d_ws, size_t ws_size,
                              hipStream_t stream) {
  const float* x     = (const float*)d_in[0];
  const float* Wqkv  = (const float*)d_in[1];
  const float* bqkv  = (const float*)d_in[2];
  const float* Wproj = (const float*)d_in[3];
  const float* bproj = (const float*)d_in[4];
  float* out = (float*)d_out;

  char* ws = (char*)d_ws;
  __bf16* xb  = (__bf16*)(ws);                   // 16 MB  x bf16 [8192][1024]; reused as vt
  __bf16* wtq = (__bf16*)(ws + 16777216);        // 6 MB   Wqkv^T [3072][1024]
  __bf16* wtp = (__bf16*)(ws + 23068672);        // 2 MB   Wproj^T [1024][1024]
  __bf16* qp  = (__bf16*)(ws + 25165824);        // 16 MB  q (B,H,T,64)
  __bf16* kp  = (__bf16*)(ws + 41943040);        // 16 MB  k
  __bf16* vp  = (__bf16*)(ws + 58720256);        // 16 MB  v
  __bf16* ao  = (__bf16*)(ws + 75497472);        // 16 MB  attn out [8192][1024]
  float2* ct  = (float2*)(ws + 92274688);        // 512 KB rope table
  __bf16* vtp = xb;                              // vt (B,H,64,T) — overwrites dead xb
  if (ws_size < 92798976) return;

  const int LDS8P = 131072;  // 2 buffers x 64KB
  hipFuncSetAttribute((const void*)gemm8p<0>,
                      hipFuncAttributeMaxDynamicSharedMemorySize, LDS8P);

  cvt_x<<<4096, 256, 0, stream>>>(x, xb);
  rope_tab_k<<<256, 256, 0, stream>>>(ct);
  transp_bf16<<<dim3(96, 32), 256, 0, stream>>>(Wqkv, wtq, 1024, 3072);
  transp_bf16<<<dim3(32, 32), 256, 0, stream>>>(Wproj, wtp, 1024, 1024);
  gemm8p<0><<<dim3(12, 32), 512, LDS8P, stream>>>(xb, wtq, bqkv, nullptr,
                                                  qp, kp, vp, ct, 8192, 3072, 1024);
  transp_v<<<dim3(32, 64), 256, 0, stream>>>(vp, vtp);
  flash_attn<<<1024, 256, 0, stream>>>(qp, kp, vtp, ao);
  gemm_bt<1><<<dim3(8, 64), 256, 0, stream>>>(ao, wtp, bproj, out, nullptr, nullptr,
                                              nullptr, nullptr, 8192, 1024, 1024);
}